// Round 6
// baseline (602.980 us; speedup 1.0000x reference)
//
#include <hip/hip_runtime.h>
#include <cstddef>

#define NN   100000
#define EE   3200000
#define GG   512
#define NBKT 1563          // ceil(NN/64) buckets of 64 nodes
#define CAP  2432          // bucket capacity: mean 2048, +8.5 sigma

typedef __attribute__((ext_vector_type(8))) short bf16x8;
typedef __attribute__((ext_vector_type(4))) float f32x4;
typedef __attribute__((ext_vector_type(8))) unsigned short u16x8;

static __device__ __forceinline__ unsigned short f2b(float f) {
  unsigned u = __float_as_uint(f);
  unsigned r = u + 0x7fffu + ((u >> 16) & 1u);   // RNE
  return (unsigned short)(r >> 16);
}
static __device__ __forceinline__ float b2f(unsigned short s) {
  return __uint_as_float(((unsigned)s) << 16);
}

// ---------------- bucket scatter: edges -> 64-node buckets ----------------
// LDS-staged: per-block LDS histogram, ONE global atomicAdd per (block,bin)
// to reserve a range, then LDS-cursor placement. Packed word = src_local<<17 | dst.
__global__ __launch_bounds__(1024) void k_bscatter(const int* __restrict__ src,
                                                   const int* __restrict__ dst,
                                                   int* __restrict__ gcur,
                                                   int* __restrict__ pk) {
  __shared__ int cnt[NBKT];
  __shared__ int base[NBKT];
  const int tid  = threadIdx.x;
  const int e_lo = blockIdx.x * (EE / 128);   // 128 blocks x 25000 edges
  const int e_hi = e_lo + (EE / 128);

  for (int b = tid; b < NBKT; b += 1024) cnt[b] = 0;
  __syncthreads();
  for (int e = e_lo + tid; e < e_hi; e += 1024)
    atomicAdd(&cnt[src[e] >> 6], 1);
  __syncthreads();
  for (int b = tid; b < NBKT; b += 1024) {
    int c = cnt[b];
    base[b] = c ? atomicAdd(&gcur[b], c) : 0;
    cnt[b] = 0;
  }
  __syncthreads();
  for (int e = e_lo + tid; e < e_hi; e += 1024) {
    int s = src[e];
    int b = s >> 6;
    int idx = base[b] + atomicAdd(&cnt[b], 1);
    if (idx < CAP) pk[b * CAP + idx] = ((s & 63) << 17) | dst[e];
  }
}

// ---------------- per-bucket prep: node-grouped csr + offsets + y = deg^-1/2*x ----
__global__ __launch_bounds__(512) void k_prep(const int* __restrict__ gcur,
                                              const int* __restrict__ pk,
                                              const float* __restrict__ x,
                                              const float* __restrict__ w1,
                                              unsigned short* __restrict__ ybf,
                                              unsigned short* __restrict__ wbf,
                                              int* __restrict__ csr,
                                              int* __restrict__ ro) {
  __shared__ int hist[64], start[65], cur[64];
  const int tid = threadIdx.x;
  const int b   = blockIdx.x;
  const int n0  = b * 64;

  if (tid < 64) hist[tid] = 0;
  __syncthreads();
  const int szc = min(gcur[b], CAP);
  for (int j = tid; j < szc; j += 512)
    atomicAdd(&hist[pk[b * CAP + j] >> 17], 1);
  __syncthreads();
  if (tid < 64) {
    int s = 0;
    for (int t = 0; t < tid; ++t) s += hist[t];
    start[tid] = s; cur[tid] = s;
    if (tid == 63) start[64] = s + hist[63];
  }
  __syncthreads();
  // node-grouped csr: scatter confined to this bucket's 9.7KB slice (L2-resident)
  for (int j = tid; j < szc; j += 512) {
    int w = pk[b * CAP + j];
    int pos = atomicAdd(&cur[w >> 17], 1);
    csr[b * CAP + pos] = w & 0x1FFFF;
  }
  if (tid < 65) ro[b * 65 + tid] = start[tid];

  // y = deg^-1/2 * x, bf16
  for (int it = 0; it < 8; ++it) {
    int idx = it * 512 + tid;          // 64 rows x 64 float4
    int row = idx >> 6, c4 = idx & 63;
    int n = n0 + row;
    if (n < NN) {
      float nr = rsqrtf((float)hist[row]);
      float4 v = ((const float4*)x)[(size_t)n * 64 + c4];
      ushort4 o;
      o.x = f2b(nr * v.x); o.y = f2b(nr * v.y); o.z = f2b(nr * v.z); o.w = f2b(nr * v.w);
      ((ushort4*)ybf)[(size_t)n * 64 + c4] = o;
    }
  }
  if (b < 64 && tid < 256) {           // W1 -> bf16
    int i = b * 256 + tid;
    float4 v = ((const float4*)w1)[i];
    ushort4 o;
    o.x = f2b(v.x); o.y = f2b(v.y); o.z = f2b(v.z); o.w = f2b(v.w);
    ((ushort4*)wbf)[i] = o;
  }
}

// ---------------- fused: gather-agg -> MFMA -> relu -> pooled atomicMax -------
// Block = one 64-node bucket, 512 threads. LDS ~34.3KB -> 4 blocks/CU;
// launch_bounds(512,8) caps VGPR at 64 so occupancy is LDS-limited (32 waves/CU).
__global__ __launch_bounds__(512, 8) void k_fused3(const int* __restrict__ ro,
                                                   const int* __restrict__ csr,
                                                   const unsigned short* __restrict__ ybf,
                                                   const unsigned short* __restrict__ wbf,
                                                   const float* __restrict__ b1,
                                                   const int* __restrict__ batch,
                                                   int* __restrict__ pooled) {
  __shared__ __align__(16) unsigned short As[64][264];
  __shared__ int ros[65];
  __shared__ int bg[64];
  const int tid  = threadIdx.x;
  const int b    = blockIdx.x;
  const int n0   = b * 64;
  const int wave = tid >> 6;
  const int lane = tid & 63;

  if (tid < 65) ros[tid] = ro[b * 65 + tid];
  if (tid >= 128 && tid < 192) bg[tid - 128] = batch[min(n0 + tid - 128, NN - 1)];
  __syncthreads();

  // ---- gather phase: half-wave per node, 4 nodes each ----
  const int half = lane >> 5, l32 = lane & 31;
  const int hw   = wave * 2 + half;   // 16 half-waves
  const u16x8* __restrict__ yr = (const u16x8*)ybf;   // row = 32 x u16x8
  const int* __restrict__ ce = csr + (size_t)b * CAP;
  for (int s = 0; s < 4; ++s) {
    const int il = hw * 4 + s;
    const int i  = n0 + il;
    u16x8 o;
    if (i < NN) {
      u16x8 sv = yr[(size_t)i * 32 + l32];   // self term y_i
      float acc[8];
#pragma unroll
      for (int c = 0; c < 8; ++c) acc[c] = b2f(sv[c]);
      int e = ros[il];
      const int e1 = ros[il + 1];
      const float ni = rsqrtf((float)(e1 - e));
      for (; e + 4 <= e1; e += 4) {
        int d0 = ce[e], d1 = ce[e + 1], d2 = ce[e + 2], d3 = ce[e + 3];
        u16x8 v0 = yr[(size_t)d0 * 32 + l32];
        u16x8 v1 = yr[(size_t)d1 * 32 + l32];
        u16x8 v2 = yr[(size_t)d2 * 32 + l32];
        u16x8 v3 = yr[(size_t)d3 * 32 + l32];
#pragma unroll
        for (int c = 0; c < 8; ++c)
          acc[c] += (b2f(v0[c]) + b2f(v1[c])) + (b2f(v2[c]) + b2f(v3[c]));
      }
      for (; e < e1; ++e) {
        u16x8 v = yr[(size_t)ce[e] * 32 + l32];
#pragma unroll
        for (int c = 0; c < 8; ++c) acc[c] += b2f(v[c]);
      }
#pragma unroll
      for (int c = 0; c < 8; ++c) o[c] = f2b(ni * acc[c]);
    } else {
#pragma unroll
      for (int c = 0; c < 8; ++c) o[c] = 0;
    }
    *(u16x8*)&As[il][l32 * 8] = o;
  }
  __syncthreads();

  // ---- MFMA phase: wave -> row-tile rt = wave&3, col-group cg = wave>>2 ----
  const int r16 = lane & 15, quad = lane >> 4;
  const int rt = wave & 3, cg = wave >> 2;
  f32x4 acc4[8];
#pragma unroll
  for (int t = 0; t < 8; ++t) acc4[t] = (f32x4){0.f, 0.f, 0.f, 0.f};
  for (int kc = 0; kc < 8; ++kc) {
    bf16x8 af = *(const bf16x8*)&As[rt * 16 + r16][kc * 32 + quad * 8];
#pragma unroll
    for (int ct = 0; ct < 8; ++ct) {
      const int n = cg * 128 + ct * 16 + r16;
      bf16x8 bf = *(const bf16x8*)(wbf + (size_t)n * 256 + kc * 32 + quad * 8);
      acc4[ct] = __builtin_amdgcn_mfma_f32_16x16x32_bf16(af, bf, acc4[ct], 0, 0, 0);
    }
  }

  // ---- epilogue: bias + relu + segmented column max + atomicMax ----
  const int row0 = rt * 16;
  const int g_lo = bg[row0], g_hi = bg[row0 + 15];
#pragma unroll
  for (int ct = 0; ct < 8; ++ct) {
    const int col = cg * 128 + ct * 16 + r16;
    const float bias = b1[col];
    float v[4];
#pragma unroll
    for (int r = 0; r < 4; ++r) v[r] = fmaxf(acc4[ct][r] + bias, 0.f);
    for (int g = g_lo; g <= g_hi; ++g) {
      float m = 0.f;
#pragma unroll
      for (int r = 0; r < 4; ++r) {
        const int row = row0 + quad * 4 + r;
        if (bg[row] == g && n0 + row < NN) m = fmaxf(m, v[r]);
      }
      m = fmaxf(m, __shfl_xor(m, 16, 64));
      m = fmaxf(m, __shfl_xor(m, 32, 64));
      if (quad == 0) atomicMax(&pooled[g * 256 + col], __float_as_int(m));
    }
  }
}

// ---------------- out = pooled @ W2^T + b2 ----------------
__global__ void k_out(const float* __restrict__ pooled, const float* __restrict__ w2,
                      const float* __restrict__ b2, float* __restrict__ out) {
  const int wave = threadIdx.x >> 6;
  const int lane = threadIdx.x & 63;
  const int g = blockIdx.x * 4 + wave;
  float4 p = ((const float4*)pooled)[g * 64 + lane];
  float4 w = ((const float4*)w2)[lane];
  float s = p.x * w.x + p.y * w.y + p.z * w.z + p.w * w.w;
  for (int off = 32; off; off >>= 1) s += __shfl_down(s, off, 64);
  if (lane == 0) out[g] = s + b2[0];
}

extern "C" void kernel_launch(void* const* d_in, const int* in_sizes, int n_in,
                              void* d_out, int out_size, void* d_ws, size_t ws_size,
                              hipStream_t stream) {
  const float* x     = (const float*)d_in[0];
  const int*   ei    = (const int*)d_in[1];
  const int*   batch = (const int*)d_in[2];
  const float* W1    = (const float*)d_in[3];
  const float* b1    = (const float*)d_in[4];
  const float* W2    = (const float*)d_in[5];
  const float* b2    = (const float*)d_in[6];
  const int* src = ei;
  const int* dst = ei + EE;
  float* out = (float*)d_out;

  // workspace carve (256B aligned)
  size_t off = 0;
  auto carve = [&](size_t bytes) -> void* {
    void* p = (char*)d_ws + off;
    off += (bytes + 255) & ~(size_t)255;
    return p;
  };
  int*   pooled = (int*)carve((size_t)GG * 256 * 4);      // fp32 bit patterns
  int*   gcur   = (int*)carve((size_t)NBKT * 4);          // adjacent: one memset
  unsigned short* ybf = (unsigned short*)carve((size_t)NN * 256 * 2);
  int*   pk     = (int*)carve((size_t)NBKT * CAP * 4);    // packed bucket edges
  int*   csr    = (int*)carve((size_t)NBKT * CAP * 4);    // node-grouped dst lists
  int*   ro     = (int*)carve((size_t)NBKT * 65 * 4);     // per-bucket row offsets
  unsigned short* wbf = (unsigned short*)carve(256 * 256 * 2);

  // zero pooled (relu floor) + gcur in one shot (contiguous carves)
  hipMemsetAsync(pooled, 0, (size_t)GG * 256 * 4 + (size_t)NBKT * 4, stream);

  k_bscatter<<<128,  1024, 0, stream>>>(src, dst, gcur, pk);
  k_prep    <<<NBKT,  512, 0, stream>>>(gcur, pk, x, W1, ybf, wbf, csr, ro);
  k_fused3  <<<NBKT,  512, 0, stream>>>(ro, csr, ybf, wbf, b1, batch, pooled);
  k_out     <<<GG / 4, 256, 0, stream>>>((const float*)pooled, W2, b2, out);
}

// Round 7
// 512.840 us; speedup vs baseline: 1.1758x; 1.1758x over previous
//
#include <hip/hip_runtime.h>
#include <cstddef>

#define NN   100000
#define EE   3200000
#define GG   512
#define NBKT 1563          // ceil(NN/64) buckets of 64 nodes
#define CAP  2432          // bucket capacity: mean 2048, +8.5 sigma

typedef __attribute__((ext_vector_type(8))) short bf16x8;
typedef __attribute__((ext_vector_type(4))) float f32x4;
typedef __attribute__((ext_vector_type(8))) unsigned short u16x8;

static __device__ __forceinline__ unsigned short f2b(float f) {
  unsigned u = __float_as_uint(f);
  unsigned r = u + 0x7fffu + ((u >> 16) & 1u);   // RNE
  return (unsigned short)(r >> 16);
}
static __device__ __forceinline__ float b2f(unsigned short s) {
  return __uint_as_float(((unsigned)s) << 16);
}

// ---------------- bucket scatter: edges -> 64-node buckets ----------------
__global__ __launch_bounds__(1024) void k_bscatter(const int* __restrict__ src,
                                                   const int* __restrict__ dst,
                                                   int* __restrict__ gcur,
                                                   int* __restrict__ pk) {
  __shared__ int cnt[NBKT];
  __shared__ int base[NBKT];
  const int tid  = threadIdx.x;
  const int e_lo = blockIdx.x * (EE / 128);   // 128 blocks x 25000 edges
  const int e_hi = e_lo + (EE / 128);

  for (int b = tid; b < NBKT; b += 1024) cnt[b] = 0;
  __syncthreads();
  for (int e = e_lo + tid; e < e_hi; e += 1024)
    atomicAdd(&cnt[src[e] >> 6], 1);
  __syncthreads();
  for (int b = tid; b < NBKT; b += 1024) {
    int c = cnt[b];
    base[b] = c ? atomicAdd(&gcur[b], c) : 0;
    cnt[b] = 0;
  }
  __syncthreads();
  for (int e = e_lo + tid; e < e_hi; e += 1024) {
    int s = src[e];
    int b = s >> 6;
    int idx = base[b] + atomicAdd(&cnt[b], 1);
    if (idx < CAP) pk[b * CAP + idx] = ((s & 63) << 17) | dst[e];
  }
}

// ---------------- per-bucket prep: node-grouped csr + offsets + y = deg^-1/2*x ----
__global__ __launch_bounds__(512) void k_prep(const int* __restrict__ gcur,
                                              const int* __restrict__ pk,
                                              const float* __restrict__ x,
                                              const float* __restrict__ w1,
                                              unsigned short* __restrict__ ybf,
                                              unsigned short* __restrict__ wbf,
                                              int* __restrict__ csr,
                                              int* __restrict__ ro) {
  __shared__ int hist[64], start[65], cur[64];
  const int tid = threadIdx.x;
  const int b   = blockIdx.x;
  const int n0  = b * 64;

  if (tid < 64) hist[tid] = 0;
  __syncthreads();
  const int szc = min(gcur[b], CAP);
  for (int j = tid; j < szc; j += 512)
    atomicAdd(&hist[pk[b * CAP + j] >> 17], 1);
  __syncthreads();
  if (tid < 64) {
    int s = 0;
    for (int t = 0; t < tid; ++t) s += hist[t];
    start[tid] = s; cur[tid] = s;
    if (tid == 63) start[64] = s + hist[63];
  }
  __syncthreads();
  // node-grouped csr: scatter confined to this bucket's 9.7KB slice (L2-resident)
  for (int j = tid; j < szc; j += 512) {
    int w = pk[b * CAP + j];
    int pos = atomicAdd(&cur[w >> 17], 1);
    csr[b * CAP + pos] = w & 0x1FFFF;
  }
  if (tid < 65) ro[b * 65 + tid] = start[tid];

  // y = deg^-1/2 * x, bf16
  for (int it = 0; it < 8; ++it) {
    int idx = it * 512 + tid;          // 64 rows x 64 float4
    int row = idx >> 6, c4 = idx & 63;
    int n = n0 + row;
    if (n < NN) {
      float nr = rsqrtf((float)hist[row]);
      float4 v = ((const float4*)x)[(size_t)n * 64 + c4];
      ushort4 o;
      o.x = f2b(nr * v.x); o.y = f2b(nr * v.y); o.z = f2b(nr * v.z); o.w = f2b(nr * v.w);
      ((ushort4*)ybf)[(size_t)n * 64 + c4] = o;
    }
  }
  if (b < 64 && tid < 256) {           // W1 -> bf16
    int i = b * 256 + tid;
    float4 v = ((const float4*)w1)[i];
    ushort4 o;
    o.x = f2b(v.x); o.y = f2b(v.y); o.z = f2b(v.z); o.w = f2b(v.w);
    ((ushort4*)wbf)[i] = o;
  }
}

// ---------------- fused: gather-agg -> MFMA -> relu -> pooled atomicMax -------
// Block = 16 nodes, 512 threads (8 waves). ONE node per half-wave (the measured
// fastest gather shape: one vmcnt drain per node slot), 8-edge unroll for MLP.
// LDS 8.5KB -> wave-limited 4 blocks/CU (~100% occupancy).
__global__ __launch_bounds__(512, 8) void k_fused4(const int* __restrict__ ro,
                                                   const int* __restrict__ csr,
                                                   const unsigned short* __restrict__ ybf,
                                                   const unsigned short* __restrict__ wbf,
                                                   const float* __restrict__ b1,
                                                   const int* __restrict__ batch,
                                                   int* __restrict__ pooled) {
  __shared__ __align__(16) unsigned short As[16][264];
  __shared__ int rs[17];
  __shared__ int bg[16];
  const int tid  = threadIdx.x;
  const int n0   = blockIdx.x * 16;              // 6250 blocks * 16 = 100000 exact
  const int bkt  = blockIdx.x >> 2;
  const int br   = (blockIdx.x & 3) * 16;        // bucket-local first row
  const int wave = tid >> 6;
  const int lane = tid & 63;

  if (tid < 17) rs[tid] = ro[bkt * 65 + br + tid];
  else if (tid >= 64 && tid < 80) bg[tid - 64] = batch[n0 + tid - 64];
  __syncthreads();

  // ---- gather phase: half-wave (32 lanes) per node, 16B/lane ----
  const int half = lane >> 5, l32 = lane & 31;
  const int il   = wave * 2 + half;              // 0..15, block-local node
  const int i    = n0 + il;
  const u16x8* __restrict__ yr = (const u16x8*)ybf;   // row = 32 x u16x8
  const int* __restrict__ ce = csr + (size_t)bkt * CAP;

  u16x8 sv = yr[(size_t)i * 32 + l32];           // self term y_i
  float acc[8];
#pragma unroll
  for (int c = 0; c < 8; ++c) acc[c] = b2f(sv[c]);

  int e = rs[il];
  const int e1 = rs[il + 1];
  const float ni = rsqrtf((float)(e1 - e));
  for (; e + 8 <= e1; e += 8) {
    int d0 = ce[e],     d1 = ce[e + 1], d2 = ce[e + 2], d3 = ce[e + 3];
    int d4 = ce[e + 4], d5 = ce[e + 5], d6 = ce[e + 6], d7 = ce[e + 7];
    u16x8 v0 = yr[(size_t)d0 * 32 + l32];
    u16x8 v1 = yr[(size_t)d1 * 32 + l32];
    u16x8 v2 = yr[(size_t)d2 * 32 + l32];
    u16x8 v3 = yr[(size_t)d3 * 32 + l32];
    u16x8 v4 = yr[(size_t)d4 * 32 + l32];
    u16x8 v5 = yr[(size_t)d5 * 32 + l32];
    u16x8 v6 = yr[(size_t)d6 * 32 + l32];
    u16x8 v7 = yr[(size_t)d7 * 32 + l32];
#pragma unroll
    for (int c = 0; c < 8; ++c)
      acc[c] += ((b2f(v0[c]) + b2f(v1[c])) + (b2f(v2[c]) + b2f(v3[c]))) +
                ((b2f(v4[c]) + b2f(v5[c])) + (b2f(v6[c]) + b2f(v7[c])));
  }
  for (; e + 4 <= e1; e += 4) {
    int d0 = ce[e], d1 = ce[e + 1], d2 = ce[e + 2], d3 = ce[e + 3];
    u16x8 v0 = yr[(size_t)d0 * 32 + l32];
    u16x8 v1 = yr[(size_t)d1 * 32 + l32];
    u16x8 v2 = yr[(size_t)d2 * 32 + l32];
    u16x8 v3 = yr[(size_t)d3 * 32 + l32];
#pragma unroll
    for (int c = 0; c < 8; ++c)
      acc[c] += (b2f(v0[c]) + b2f(v1[c])) + (b2f(v2[c]) + b2f(v3[c]));
  }
  for (; e < e1; ++e) {
    u16x8 v = yr[(size_t)ce[e] * 32 + l32];
#pragma unroll
    for (int c = 0; c < 8; ++c) acc[c] += b2f(v[c]);
  }
  u16x8 o;
#pragma unroll
  for (int c = 0; c < 8; ++c) o[c] = f2b(ni * acc[c]);
  *(u16x8*)&As[il][l32 * 8] = o;
  __syncthreads();

  // ---- MFMA phase: wave w covers cols [w*32, w*32+32) of the 16x256 tile ----
  const int r16 = lane & 15, quad = lane >> 4;
  f32x4 acc4[2];
#pragma unroll
  for (int t = 0; t < 2; ++t) acc4[t] = (f32x4){0.f, 0.f, 0.f, 0.f};
  for (int kc = 0; kc < 8; ++kc) {
    bf16x8 af = *(const bf16x8*)&As[r16][kc * 32 + quad * 8];
#pragma unroll
    for (int ct = 0; ct < 2; ++ct) {
      const int n = wave * 32 + ct * 16 + r16;
      bf16x8 bf = *(const bf16x8*)(wbf + (size_t)n * 256 + kc * 32 + quad * 8);
      acc4[ct] = __builtin_amdgcn_mfma_f32_16x16x32_bf16(af, bf, acc4[ct], 0, 0, 0);
    }
  }

  // ---- epilogue: bias + relu + per-graph column max + atomicMax ----
  const int g0 = bg[0], g15 = bg[15];
  if (g0 == g15) {
#pragma unroll
    for (int ct = 0; ct < 2; ++ct) {
      const int col = wave * 32 + ct * 16 + r16;
      const float bias = b1[col];
      float m = 0.f;   // relu identity
#pragma unroll
      for (int r = 0; r < 4; ++r) m = fmaxf(m, acc4[ct][r] + bias);
      m = fmaxf(m, __shfl_xor(m, 16, 64));
      m = fmaxf(m, __shfl_xor(m, 32, 64));
      if (quad == 0) atomicMax(&pooled[g0 * 256 + col], __float_as_int(m));
    }
  } else {
#pragma unroll
    for (int ct = 0; ct < 2; ++ct) {
      const int col = wave * 32 + ct * 16 + r16;
      const float bias = b1[col];
      for (int g = g0; g <= g15; ++g) {
        float m = 0.f;
#pragma unroll
        for (int r = 0; r < 4; ++r) {
          const int row = quad * 4 + r;
          float v = fmaxf(acc4[ct][r] + bias, 0.f);
          if (bg[row] == g) m = fmaxf(m, v);
        }
        m = fmaxf(m, __shfl_xor(m, 16, 64));
        m = fmaxf(m, __shfl_xor(m, 32, 64));
        if (quad == 0) atomicMax(&pooled[g * 256 + col], __float_as_int(m));
      }
    }
  }
}

// ---------------- out = pooled @ W2^T + b2 ----------------
__global__ void k_out(const float* __restrict__ pooled, const float* __restrict__ w2,
                      const float* __restrict__ b2, float* __restrict__ out) {
  const int wave = threadIdx.x >> 6;
  const int lane = threadIdx.x & 63;
  const int g = blockIdx.x * 4 + wave;
  float4 p = ((const float4*)pooled)[g * 64 + lane];
  float4 w = ((const float4*)w2)[lane];
  float s = p.x * w.x + p.y * w.y + p.z * w.z + p.w * w.w;
  for (int off = 32; off; off >>= 1) s += __shfl_down(s, off, 64);
  if (lane == 0) out[g] = s + b2[0];
}

extern "C" void kernel_launch(void* const* d_in, const int* in_sizes, int n_in,
                              void* d_out, int out_size, void* d_ws, size_t ws_size,
                              hipStream_t stream) {
  const float* x     = (const float*)d_in[0];
  const int*   ei    = (const int*)d_in[1];
  const int*   batch = (const int*)d_in[2];
  const float* W1    = (const float*)d_in[3];
  const float* b1    = (const float*)d_in[4];
  const float* W2    = (const float*)d_in[5];
  const float* b2    = (const float*)d_in[6];
  const int* src = ei;
  const int* dst = ei + EE;
  float* out = (float*)d_out;

  // workspace carve (256B aligned)
  size_t off = 0;
  auto carve = [&](size_t bytes) -> void* {
    void* p = (char*)d_ws + off;
    off += (bytes + 255) & ~(size_t)255;
    return p;
  };
  int*   pooled = (int*)carve((size_t)GG * 256 * 4);      // fp32 bit patterns
  int*   gcur   = (int*)carve((size_t)NBKT * 4);          // adjacent: one memset
  unsigned short* ybf = (unsigned short*)carve((size_t)NN * 256 * 2);
  int*   pk     = (int*)carve((size_t)NBKT * CAP * 4);    // packed bucket edges
  int*   csr    = (int*)carve((size_t)NBKT * CAP * 4);    // node-grouped dst lists
  int*   ro     = (int*)carve((size_t)NBKT * 65 * 4);     // per-bucket row offsets
  unsigned short* wbf = (unsigned short*)carve(256 * 256 * 2);

  // zero pooled (relu floor) + gcur in one shot (contiguous carves)
  hipMemsetAsync(pooled, 0, (size_t)GG * 256 * 4 + (size_t)NBKT * 4, stream);

  k_bscatter<<<128,  1024, 0, stream>>>(src, dst, gcur, pk);
  k_prep    <<<NBKT,  512, 0, stream>>>(gcur, pk, x, W1, ybf, wbf, csr, ro);
  k_fused4  <<<NN / 16, 512, 0, stream>>>(ro, csr, ybf, wbf, b1, batch, pooled);
  k_out     <<<GG / 4, 256, 0, stream>>>((const float*)pooled, W2, b2, out);
}

// Round 8
// 472.028 us; speedup vs baseline: 1.2774x; 1.0865x over previous
//
#include <hip/hip_runtime.h>
#include <cstddef>

#define NN    100000
#define EE    3200000
#define GG    512
#define NBKT  1563         // ceil(NN/64) fine buckets of 64 nodes
#define CAP   2432         // fine bucket capacity: mean 2048, +8.5 sigma
#define CBINS 49           // coarse bins of 2048 nodes
#define CCAP  68000        // coarse capacity: mean 65306, +10 sigma
#define TT    4096         // LDS sort tile (edges)

typedef __attribute__((ext_vector_type(8))) short bf16x8;
typedef __attribute__((ext_vector_type(4))) float f32x4;
typedef __attribute__((ext_vector_type(8))) unsigned short u16x8;

static __device__ __forceinline__ unsigned short f2b(float f) {
  unsigned u = __float_as_uint(f);
  unsigned r = u + 0x7fffu + ((u >> 16) & 1u);   // RNE
  return (unsigned short)(r >> 16);
}
static __device__ __forceinline__ float b2f(unsigned short s) {
  return __uint_as_float(((unsigned)s) << 16);
}

// ---------------- pass 1: edges -> 49 coarse bins (LDS tile sort) ----------------
// Tile of 4096 edges is counting-sorted in LDS, then each bin's run is copied to
// its reserved global range as a CONTIGUOUS coalesced write (write-once lines) --
// this removes the 3.2M random-line 4B writes that made the old bscatter slow.
__global__ __launch_bounds__(1024, 4) void k_split1(const int* __restrict__ src,
                                                    const int* __restrict__ dst,
                                                    int* __restrict__ ccur,
                                                    int* __restrict__ cpk) {
  __shared__ int hist[CBINS], st[CBINS], cur[CBINS], gbase[CBINS];
  __shared__ int sorted[TT];
  __shared__ unsigned char binof[TT];
  const int tid  = threadIdx.x;
  const int e_lo = blockIdx.x * (EE / 256);   // 12500 edges per block
  const int e_hi = e_lo + (EE / 256);

  for (int t0 = e_lo; t0 < e_hi; t0 += TT) {
    const int tc = min(TT, e_hi - t0);
    for (int k = tid; k < CBINS; k += 1024) hist[k] = 0;
    __syncthreads();
    int myk[4], myw[4];
#pragma unroll
    for (int r = 0; r < 4; ++r) {
      int j = r * 1024 + tid;
      myk[r] = -1;
      if (j < tc) {
        int s = src[t0 + j], d = dst[t0 + j];
        myk[r] = s >> 11;                       // coarse bin
        myw[r] = ((s & 2047) << 17) | d;        // (src_local11, dst17)
        atomicAdd(&hist[myk[r]], 1);
      }
    }
    __syncthreads();
    if (tid < CBINS) {
      int s = 0;
      for (int t = 0; t < tid; ++t) s += hist[t];
      st[tid] = s; cur[tid] = s;
    }
    __syncthreads();
#pragma unroll
    for (int r = 0; r < 4; ++r) {
      if (myk[r] >= 0) {
        int pos = atomicAdd(&cur[myk[r]], 1);
        sorted[pos] = myw[r];
        binof[pos] = (unsigned char)myk[r];
      }
    }
    __syncthreads();
    if (tid < CBINS) {
      int c = cur[tid] - st[tid];
      gbase[tid] = c ? atomicAdd(&ccur[tid], c) : 0;
    }
    __syncthreads();
    for (int j = tid; j < tc; j += 1024) {
      int k = binof[j];
      int idx = gbase[k] + (j - st[k]);
      if (idx < CCAP) cpk[(size_t)k * CCAP + idx] = sorted[j];
    }
    __syncthreads();
  }
}

// ---------------- pass 2: coarse bin -> 32 fine buckets (LDS tile sort) ---------
// Produces exactly the pk/gcur layout k_prep consumes.
__global__ __launch_bounds__(1024, 4) void k_split2(const int* __restrict__ ccur,
                                                    const int* __restrict__ cpk,
                                                    int* __restrict__ gcur,
                                                    int* __restrict__ pk) {
  __shared__ int hist[32], st[32], cur[32], gbase[32];
  __shared__ int sorted[TT];
  __shared__ unsigned char binof[TT];
  const int tid  = threadIdx.x;
  const int c    = blockIdx.x >> 4;            // 49 coarse bins x 16 slices
  const int sl   = blockIdx.x & 15;
  const int clen = min(ccur[c], CCAP);
  const int lo   = (int)((long long)clen * sl / 16);
  const int hi   = (int)((long long)clen * (sl + 1) / 16);
  const int* __restrict__ cp = cpk + (size_t)c * CCAP;

  for (int t0 = lo; t0 < hi; t0 += TT) {
    const int tc = min(TT, hi - t0);
    if (tid < 32) hist[tid] = 0;
    __syncthreads();
    int myk[4], myw[4];
#pragma unroll
    for (int r = 0; r < 4; ++r) {
      int j = r * 1024 + tid;
      myk[r] = -1;
      if (j < tc) {
        int w    = cp[t0 + j];
        int sl11 = w >> 17;
        myk[r] = sl11 >> 6;                      // fine bucket within coarse
        myw[r] = ((sl11 & 63) << 17) | (w & 0x1FFFF);
        atomicAdd(&hist[myk[r]], 1);
      }
    }
    __syncthreads();
    if (tid < 32) {
      int s = 0;
      for (int t = 0; t < tid; ++t) s += hist[t];
      st[tid] = s; cur[tid] = s;
    }
    __syncthreads();
#pragma unroll
    for (int r = 0; r < 4; ++r) {
      if (myk[r] >= 0) {
        int pos = atomicAdd(&cur[myk[r]], 1);
        sorted[pos] = myw[r];
        binof[pos] = (unsigned char)myk[r];
      }
    }
    __syncthreads();
    if (tid < 32) {
      int cnum = cur[tid] - st[tid];
      gbase[tid] = cnum ? atomicAdd(&gcur[c * 32 + tid], cnum) : 0;
    }
    __syncthreads();
    for (int j = tid; j < tc; j += 1024) {
      int k   = binof[j];
      int idx = gbase[k] + (j - st[k]);
      if (idx < CAP) pk[(size_t)(c * 32 + k) * CAP + idx] = sorted[j];
    }
    __syncthreads();
  }
}

// ---------------- per-bucket prep: node-grouped csr + offsets + y = deg^-1/2*x ----
__global__ __launch_bounds__(512) void k_prep(const int* __restrict__ gcur,
                                              const int* __restrict__ pk,
                                              const float* __restrict__ x,
                                              const float* __restrict__ w1,
                                              unsigned short* __restrict__ ybf,
                                              unsigned short* __restrict__ wbf,
                                              int* __restrict__ csr,
                                              int* __restrict__ ro) {
  __shared__ int hist[64], start[65], cur[64];
  const int tid = threadIdx.x;
  const int b   = blockIdx.x;
  const int n0  = b * 64;

  if (tid < 64) hist[tid] = 0;
  __syncthreads();
  const int szc = min(gcur[b], CAP);
  for (int j = tid; j < szc; j += 512)
    atomicAdd(&hist[pk[b * CAP + j] >> 17], 1);
  __syncthreads();
  if (tid < 64) {
    int s = 0;
    for (int t = 0; t < tid; ++t) s += hist[t];
    start[tid] = s; cur[tid] = s;
    if (tid == 63) start[64] = s + hist[63];
  }
  __syncthreads();
  for (int j = tid; j < szc; j += 512) {
    int w = pk[b * CAP + j];
    int pos = atomicAdd(&cur[w >> 17], 1);
    csr[b * CAP + pos] = w & 0x1FFFF;
  }
  if (tid < 65) ro[b * 65 + tid] = start[tid];

  for (int it = 0; it < 8; ++it) {
    int idx = it * 512 + tid;          // 64 rows x 64 float4
    int row = idx >> 6, c4 = idx & 63;
    int n = n0 + row;
    if (n < NN) {
      float nr = rsqrtf((float)hist[row]);
      float4 v = ((const float4*)x)[(size_t)n * 64 + c4];
      ushort4 o;
      o.x = f2b(nr * v.x); o.y = f2b(nr * v.y); o.z = f2b(nr * v.z); o.w = f2b(nr * v.w);
      ((ushort4*)ybf)[(size_t)n * 64 + c4] = o;
    }
  }
  if (b < 64 && tid < 256) {           // W1 -> bf16
    int i = b * 256 + tid;
    float4 v = ((const float4*)w1)[i];
    ushort4 o;
    o.x = f2b(v.x); o.y = f2b(v.y); o.z = f2b(v.z); o.w = f2b(v.w);
    ((ushort4*)wbf)[i] = o;
  }
}

// ---------------- fused: gather-agg -> MFMA -> relu -> pooled atomicMax -------
// Block = 16 nodes, 512 threads. ONE node per half-wave (measured-fastest gather
// shape), 8-edge unroll. LDS 8.5KB -> wave-limited ~100% occupancy.
__global__ __launch_bounds__(512, 8) void k_fused4(const int* __restrict__ ro,
                                                   const int* __restrict__ csr,
                                                   const unsigned short* __restrict__ ybf,
                                                   const unsigned short* __restrict__ wbf,
                                                   const float* __restrict__ b1,
                                                   const int* __restrict__ batch,
                                                   int* __restrict__ pooled) {
  __shared__ __align__(16) unsigned short As[16][264];
  __shared__ int rs[17];
  __shared__ int bg[16];
  const int tid  = threadIdx.x;
  const int n0   = blockIdx.x * 16;              // 6250 blocks * 16 = 100000 exact
  const int bkt  = blockIdx.x >> 2;
  const int br   = (blockIdx.x & 3) * 16;        // bucket-local first row
  const int wave = tid >> 6;
  const int lane = tid & 63;

  if (tid < 17) rs[tid] = ro[bkt * 65 + br + tid];
  else if (tid >= 64 && tid < 80) bg[tid - 64] = batch[n0 + tid - 64];
  __syncthreads();

  const int half = lane >> 5, l32 = lane & 31;
  const int il   = wave * 2 + half;              // 0..15, block-local node
  const int i    = n0 + il;
  const u16x8* __restrict__ yr = (const u16x8*)ybf;   // row = 32 x u16x8
  const int* __restrict__ ce = csr + (size_t)bkt * CAP;

  u16x8 sv = yr[(size_t)i * 32 + l32];           // self term y_i
  float acc[8];
#pragma unroll
  for (int c = 0; c < 8; ++c) acc[c] = b2f(sv[c]);

  int e = rs[il];
  const int e1 = rs[il + 1];
  const float ni = rsqrtf((float)(e1 - e));
  for (; e + 8 <= e1; e += 8) {
    int d0 = ce[e],     d1 = ce[e + 1], d2 = ce[e + 2], d3 = ce[e + 3];
    int d4 = ce[e + 4], d5 = ce[e + 5], d6 = ce[e + 6], d7 = ce[e + 7];
    u16x8 v0 = yr[(size_t)d0 * 32 + l32];
    u16x8 v1 = yr[(size_t)d1 * 32 + l32];
    u16x8 v2 = yr[(size_t)d2 * 32 + l32];
    u16x8 v3 = yr[(size_t)d3 * 32 + l32];
    u16x8 v4 = yr[(size_t)d4 * 32 + l32];
    u16x8 v5 = yr[(size_t)d5 * 32 + l32];
    u16x8 v6 = yr[(size_t)d6 * 32 + l32];
    u16x8 v7 = yr[(size_t)d7 * 32 + l32];
#pragma unroll
    for (int c = 0; c < 8; ++c)
      acc[c] += ((b2f(v0[c]) + b2f(v1[c])) + (b2f(v2[c]) + b2f(v3[c]))) +
                ((b2f(v4[c]) + b2f(v5[c])) + (b2f(v6[c]) + b2f(v7[c])));
  }
  for (; e + 4 <= e1; e += 4) {
    int d0 = ce[e], d1 = ce[e + 1], d2 = ce[e + 2], d3 = ce[e + 3];
    u16x8 v0 = yr[(size_t)d0 * 32 + l32];
    u16x8 v1 = yr[(size_t)d1 * 32 + l32];
    u16x8 v2 = yr[(size_t)d2 * 32 + l32];
    u16x8 v3 = yr[(size_t)d3 * 32 + l32];
#pragma unroll
    for (int c = 0; c < 8; ++c)
      acc[c] += (b2f(v0[c]) + b2f(v1[c])) + (b2f(v2[c]) + b2f(v3[c]));
  }
  for (; e < e1; ++e) {
    u16x8 v = yr[(size_t)ce[e] * 32 + l32];
#pragma unroll
    for (int c = 0; c < 8; ++c) acc[c] += b2f(v[c]);
  }
  u16x8 o;
#pragma unroll
  for (int c = 0; c < 8; ++c) o[c] = f2b(ni * acc[c]);
  *(u16x8*)&As[il][l32 * 8] = o;
  __syncthreads();

  // ---- MFMA phase: wave w covers cols [w*32, w*32+32) of the 16x256 tile ----
  const int r16 = lane & 15, quad = lane >> 4;
  f32x4 acc4[2];
#pragma unroll
  for (int t = 0; t < 2; ++t) acc4[t] = (f32x4){0.f, 0.f, 0.f, 0.f};
  for (int kc = 0; kc < 8; ++kc) {
    bf16x8 af = *(const bf16x8*)&As[r16][kc * 32 + quad * 8];
#pragma unroll
    for (int ct = 0; ct < 2; ++ct) {
      const int n = wave * 32 + ct * 16 + r16;
      bf16x8 bf = *(const bf16x8*)(wbf + (size_t)n * 256 + kc * 32 + quad * 8);
      acc4[ct] = __builtin_amdgcn_mfma_f32_16x16x32_bf16(af, bf, acc4[ct], 0, 0, 0);
    }
  }

  // ---- epilogue: bias + relu + per-graph column max + atomicMax ----
  const int g0 = bg[0], g15 = bg[15];
  if (g0 == g15) {
#pragma unroll
    for (int ct = 0; ct < 2; ++ct) {
      const int col = wave * 32 + ct * 16 + r16;
      const float bias = b1[col];
      float m = 0.f;   // relu identity
#pragma unroll
      for (int r = 0; r < 4; ++r) m = fmaxf(m, acc4[ct][r] + bias);
      m = fmaxf(m, __shfl_xor(m, 16, 64));
      m = fmaxf(m, __shfl_xor(m, 32, 64));
      if (quad == 0) atomicMax(&pooled[g0 * 256 + col], __float_as_int(m));
    }
  } else {
#pragma unroll
    for (int ct = 0; ct < 2; ++ct) {
      const int col = wave * 32 + ct * 16 + r16;
      const float bias = b1[col];
      for (int g = g0; g <= g15; ++g) {
        float m = 0.f;
#pragma unroll
        for (int r = 0; r < 4; ++r) {
          const int row = quad * 4 + r;
          float v = fmaxf(acc4[ct][r] + bias, 0.f);
          if (bg[row] == g) m = fmaxf(m, v);
        }
        m = fmaxf(m, __shfl_xor(m, 16, 64));
        m = fmaxf(m, __shfl_xor(m, 32, 64));
        if (quad == 0) atomicMax(&pooled[g * 256 + col], __float_as_int(m));
      }
    }
  }
}

// ---------------- out = pooled @ W2^T + b2 ----------------
__global__ void k_out(const float* __restrict__ pooled, const float* __restrict__ w2,
                      const float* __restrict__ b2, float* __restrict__ out) {
  const int wave = threadIdx.x >> 6;
  const int lane = threadIdx.x & 63;
  const int g = blockIdx.x * 4 + wave;
  float4 p = ((const float4*)pooled)[g * 64 + lane];
  float4 w = ((const float4*)w2)[lane];
  float s = p.x * w.x + p.y * w.y + p.z * w.z + p.w * w.w;
  for (int off = 32; off; off >>= 1) s += __shfl_down(s, off, 64);
  if (lane == 0) out[g] = s + b2[0];
}

extern "C" void kernel_launch(void* const* d_in, const int* in_sizes, int n_in,
                              void* d_out, int out_size, void* d_ws, size_t ws_size,
                              hipStream_t stream) {
  const float* x     = (const float*)d_in[0];
  const int*   ei    = (const int*)d_in[1];
  const int*   batch = (const int*)d_in[2];
  const float* W1    = (const float*)d_in[3];
  const float* b1    = (const float*)d_in[4];
  const float* W2    = (const float*)d_in[5];
  const float* b2    = (const float*)d_in[6];
  const int* src = ei;
  const int* dst = ei + EE;
  float* out = (float*)d_out;

  // workspace carve (256B aligned)
  size_t off = 0;
  auto carve = [&](size_t bytes) -> void* {
    void* p = (char*)d_ws + off;
    off += (bytes + 255) & ~(size_t)255;
    return p;
  };
  int*   pooled = (int*)carve((size_t)GG * 256 * 4);       // fp32 bit patterns
  int*   gcur   = (int*)carve((size_t)NBKT * 4);           // fine bucket counts
  int*   ccur   = (int*)carve((size_t)CBINS * 4);          // coarse bin counts
  const size_t zlen = off;                                  // one memset covers all 3
  unsigned short* ybf = (unsigned short*)carve((size_t)NN * 256 * 2);
  int*   cpk    = (int*)carve((size_t)CBINS * CCAP * 4);   // coarse-sorted edges
  int*   pk     = (int*)carve((size_t)NBKT * CAP * 4);     // fine bucket edges
  int*   csr    = (int*)carve((size_t)NBKT * CAP * 4);     // node-grouped dst lists
  int*   ro     = (int*)carve((size_t)NBKT * 65 * 4);      // per-bucket row offsets
  unsigned short* wbf = (unsigned short*)carve(256 * 256 * 2);

  hipMemsetAsync(pooled, 0, zlen, stream);   // pooled zeros (relu floor) + cursors

  k_split1<<<256,        1024, 0, stream>>>(src, dst, ccur, cpk);
  k_split2<<<CBINS * 16, 1024, 0, stream>>>(ccur, cpk, gcur, pk);
  k_prep  <<<NBKT,        512, 0, stream>>>(gcur, pk, x, W1, ybf, wbf, csr, ro);
  k_fused4<<<NN / 16,     512, 0, stream>>>(ro, csr, ybf, wbf, b1, batch, pooled);
  k_out   <<<GG / 4,      256, 0, stream>>>((const float*)pooled, W2, b2, out);
}